// Round 3
// baseline (242.758 us; speedup 1.0000x reference)
//
#include <hip/hip_runtime.h>
#include <math.h>
#include <stdint.h>

#define NB 15
#define NCOPY 8                   // spread accumulator copies (contention /8)
#define ACCSTRIDE 64              // floats per copy (line-separated)

// d_ws: NCOPY copies of [0..14]=counts, [15..29]=sum_u, [30..44]=sum_err

// Direct global->register streaming. No LDS staging: every logit byte is
// consumed exactly once by exactly one thread (no reuse), so DMA->LDS->reg
// was pure overhead (barriers, vmcnt drains, 45KB LDS -> 3 blocks/CU).
// Row r's 40 bytes are 8-aligned -> 5x dwordx2; a wave's 5 loads cover a
// dense 2560B span, L1 absorbs the stride-40 interleave.
__global__ __launch_bounds__(256) void bin_kernel(
    const float* __restrict__ logits,
    const int* __restrict__ labels,
    float* __restrict__ acc, int N)
{
    __shared__ float s_acc[3 * NB];
    const int t = threadIdx.x;
    if (t < 3 * NB) s_acc[t] = 0.0f;
    __syncthreads();

    const int lane = t & 63;

    int   pk[NB];                          // count | (err<<16)
    float su[NB];
#pragma unroll
    for (int b = 0; b < NB; ++b) { pk[b] = 0; su[b] = 0.0f; }

    const long long stride = (long long)gridDim.x * 256;

    for (long long r = (long long)blockIdx.x * 256 + t; r < N; r += stride) {
        // ---- 10 logits straight to registers (5x dwordx2, 8-aligned) ----
        const float2* p = (const float2*)(logits + r * 10);
        float lv[10];
#pragma unroll
        for (int j = 0; j < 5; ++j) { float2 w = p[j]; lv[2*j] = w.x; lv[2*j+1] = w.y; }
        const int lab = labels[r];

        // label logit via compare-select chain (replaces dynamic LDS read)
        float lvl = lv[0];
#pragma unroll
        for (int j = 1; j < 10; ++j) lvl = (lab == j) ? lv[j] : lvl;

        // ---- row stats ----
        float m = lv[0];
#pragma unroll
        for (int j = 1; j < 10; ++j) m = fmaxf(m, lv[j]);

        const float c = 1.44269504088896340736f;
        float mc = m * c;
        float Z = 0.0f, S = 0.0f;
#pragma unroll
        for (int j = 0; j < 10; ++j) {
            float e = exp2f(fmaf(lv[j], c, -mc));
            Z += e;
            S = fmaf(e, e, S);
        }
        float ratio = S * __builtin_amdgcn_rcpf(Z * Z);   // sum(p^2)
        float u = -log2f(ratio + 1e-12f);

        bool valid = (u >= 0.0f) && (u < 1.0f);
        int bin = -1;
        if (valid) {
            bin = (int)(u * 15.0f);
            if (bin > 14) bin = 14;
        }
        if (!valid) u = 0.0f;
        int e10 = (lvl != m) ? 1 : 0;      // wrong iff label's logit isn't the max
        int inc = 1 + (e10 << 16);

#pragma unroll
        for (int b = 0; b < NB; ++b) {
            bool mb = (bin == b);
            pk[b] += mb ? inc : 0;
            su[b] += mb ? u : 0.0f;
        }
    }

    // ---- once-per-block: wave butterfly -> shared atomics -> spread global atomics
#pragma unroll
    for (int b = 0; b < NB; ++b) {
        int   p = pk[b];
        float s = su[b];
#pragma unroll
        for (int off = 1; off < 64; off <<= 1) {
            p += __shfl_xor(p, off, 64);
            s += __shfl_xor(s, off, 64);
        }
        if (lane == 0) {
            atomicAdd(&s_acc[b],          (float)(p & 0xFFFF));
            atomicAdd(&s_acc[NB + b],     s);
            atomicAdd(&s_acc[2 * NB + b], (float)(p >> 16));
        }
    }
    __syncthreads();
    if (t < 3 * NB) {
        float v = s_acc[t];
        if (v != 0.0f)
            atomicAdd(&acc[(blockIdx.x & (NCOPY - 1)) * ACCSTRIDE + t], v);
    }
}

__global__ void finalize_kernel(const float* __restrict__ acc,
                                float* __restrict__ out, float n)
{
    int b = threadIdx.x;
    float gap = 0.0f;
    if (b < NB) {
        float cnt = 0.0f, sumu = 0.0f, serr = 0.0f;
#pragma unroll
        for (int c = 0; c < NCOPY; ++c) {
            cnt  += acc[c * ACCSTRIDE + b];
            sumu += acc[c * ACCSTRIDE + NB + b];
            serr += acc[c * ACCSTRIDE + 2 * NB + b];
        }
        if (cnt > 0.0f) {
            float u_b   = sumu / cnt;
            float err_b = serr / cnt;
            float inner = 2.0f * exp2f(-u_b) - 1.0f;
            if (inner < 0.0f) inner = 0.0f;
            float r_ref = 0.5f * (1.0f - sqrtf(inner));
            gap = fabsf(err_b - r_ref) * (cnt / n);
        }
    }
#pragma unroll
    for (int off = 32; off >= 1; off >>= 1)
        gap += __shfl_xor(gap, off, 64);
    if (b == 0) out[0] = gap;
}

extern "C" void kernel_launch(void* const* d_in, const int* in_sizes, int n_in,
                              void* d_out, int out_size, void* d_ws, size_t ws_size,
                              hipStream_t stream)
{
    const float* logits = (const float*)d_in[0];
    const int*   labels = (const int*)d_in[1];
    const int N = in_sizes[1];                  // labels count = number of rows

    float* acc = (float*)d_ws;                  // NCOPY * ACCSTRIDE floats
    hipMemsetAsync(acc, 0, NCOPY * ACCSTRIDE * sizeof(float), stream);

    // 1024 blocks (4/CU) -> guaranteed fully resident regardless of VGPR count;
    // grid-stride persistent loop, ~16 row-iters/thread. 16 waves/CU keep
    // ~40KB/CU of loads in flight >> ~9KB needed for 6.3 TB/s at 900cy latency.
    int blocks = (N + 255) / 256;
    if (blocks > 1024) blocks = 1024;
    if (blocks < 1) blocks = 1;
    bin_kernel<<<blocks, 256, 0, stream>>>(logits, labels, acc, N);
    finalize_kernel<<<1, 64, 0, stream>>>(acc, (float*)d_out, (float)N);
}